// Round 8
// baseline (219.176 us; speedup 1.0000x reference)
//
#include <hip/hip_runtime.h>
#include <hip/hip_bf16.h>
#include <math.h>

#define C_CLASSES 100000
#define EMBED     384
#define BATCH     512
#define S_SCALE   64.0f
#define COS_M_    0.8775825618903728f
#define SIN_M_    0.479425538604203f
#define TH_       (-0.8775825618903728f)
#define MM_       0.2397127693021015f
#define EPS_      1e-7f
#define LOG2E_    1.4426950408889634f
#define LN2_      0.6931471805599453f
#define BIGZ_     92.33261191693459f      /* 64 * log2(e) */

#define CT    32                           // classes per block
#define NCHK  3125                         // 100000 / 32, exact

typedef __attribute__((ext_vector_type(8))) short bf16x8;
typedef __attribute__((ext_vector_type(4))) float f32x4;

#define AS1 __attribute__((address_space(1)))
#define AS3 __attribute__((address_space(3)))

__device__ inline ushort f2bf(float f) {
    unsigned u = __float_as_uint(f);
    unsigned r = (u + 0x7fffu + ((u >> 16) & 1u)) >> 16;   // RNE
    return (ushort)r;
}

// ---------------------------------------------------------------------------
// Kernel 0: convert E to bf16, packed in MFMA A-fragment order:
//   eP[((tile*12 + ks)*64 + lane)*8 + j] = bf16(E[tile*16 + (lane&15)]
//                                               [ks*32 + (lane>>4)*8 + j])
// ---------------------------------------------------------------------------
__global__ __launch_bounds__(256)
void cvt_pack_e(const float* __restrict__ emb, ushort* __restrict__ eP)
{
    int t = blockIdx.x * 256 + threadIdx.x;      // 0 .. 24575
    int lane = t & 63;
    int grp  = t >> 6;                           // tile*12 + ks
    int tile = grp / 12, ks = grp % 12;
    int lr = lane & 15, lg = lane >> 4;
    int row = tile * 16 + lr;
    int col = ks * 32 + lg * 8;
    const float4* src = (const float4*)(emb + (size_t)row * EMBED + col);
    float4 v0 = src[0], v1 = src[1];
    ushort4 o0, o1;
    o0.x = f2bf(v0.x); o0.y = f2bf(v0.y); o0.z = f2bf(v0.z); o0.w = f2bf(v0.w);
    o1.x = f2bf(v1.x); o1.y = f2bf(v1.y); o1.z = f2bf(v1.z); o1.w = f2bf(v1.w);
    ((ushort4*)eP)[t * 2]     = o0;
    ((ushort4*)eP)[t * 2 + 1] = o1;
}

// ---------------------------------------------------------------------------
// Kernel 1: fully fused. Per block (32 classes):
//   DMA raw fp32 W chunk -> LDS (48 KB, zero VGPR)  -> sync
//   normalize (16 lanes/row) -> bf16 B-fragment-packed LDS (24 KB) -> sync
//   MFMA (8 waves x 4mt x 2nt x 12ks), A-frags from L2-resident eP
//   margin + fixed-max partial LSE epilogue.
// grid = 3125 x 512; LDS 72 KB -> 2 blocks/CU (stage/compute overlap).
// ---------------------------------------------------------------------------
__global__ __launch_bounds__(512, 4)
void arc_fused(const ushort* __restrict__ eP, const int* __restrict__ labels,
               const float* __restrict__ weight,
               float* __restrict__ psum, float* __restrict__ zlabel)
{
    __shared__ float  Raw[CT * EMBED];              // 49152 B
    __shared__ ushort Bl[(CT / 16) * 12 * 512];     // 24576 B

    const int tid = threadIdx.x;
    const int blk = blockIdx.x;
    const int c0  = blk * CT;

    // ---- phase 1: DMA the raw fp32 chunk (48 KB) into LDS ----
    {
        const AS1 uint* gbase = (const AS1 uint*)(weight + (size_t)c0 * EMBED);
        #pragma unroll
        for (int j = 0; j < 6; ++j) {
            const AS1 uint* gp = gbase + (size_t)(j * 512 + tid) * 4;
            AS3 uint* lp = (AS3 uint*)Raw + (size_t)(j * 512 + (tid & ~63)) * 4;
            __builtin_amdgcn_global_load_lds(gp, lp, 16, 0, 0);
        }
    }
    __syncthreads();     // drains vmcnt(0): raw chunk visible

    // ---- phase 2: normalize rows, write bf16 B-fragment-packed LDS ----
    {
        const int c = tid >> 4;          // class within chunk (0..31)
        const int p = tid & 15;          // 16 lanes per class
        const float4* R4 = (const float4*)Raw;      // 96 float4 per row
        float4 v[6];
        float ss = 0.f;
        #pragma unroll
        for (int i = 0; i < 6; ++i) {
            v[i] = R4[c * 96 + p + 16 * i];
            ss += v[i].x * v[i].x + v[i].y * v[i].y
                + v[i].z * v[i].z + v[i].w * v[i].w;
        }
        #pragma unroll
        for (int d = 1; d < 16; d <<= 1) ss += __shfl_xor(ss, d, 64);
        const float inv = (ss > 0.f) ? rsqrtf(ss) : 0.f;

        const int t2 = c >> 4, cl = c & 15;
        #pragma unroll
        for (int i = 0; i < 6; ++i) {
            int q   = p + 16 * i;            // quad index 0..95 (k = 4q..4q+3)
            int ks  = q >> 3;
            int lgp = (q >> 1) & 3;
            int jo  = (q & 1) * 4;
            ushort4 o;
            o.x = f2bf(v[i].x * inv); o.y = f2bf(v[i].y * inv);
            o.z = f2bf(v[i].z * inv); o.w = f2bf(v[i].w * inv);
            *(ushort4*)&Bl[(size_t)(((t2 * 12 + ks) * 64) + cl + 16 * lgp) * 8 + jo] = o;
        }
    }
    __syncthreads();     // packed B ready

    // ---- phase 3: MFMA, 8 waves x (4 Mtiles x 2 Ntiles), K=384 ----
    const int wid = tid >> 6, l = tid & 63;
    const int lr  = l & 15,  lg = l >> 4;

    const ushort* abase = eP + ((size_t)(wid * 4) * 12 * 64 + l) * 8;

    f32x4 acc[4][2];
    #pragma unroll
    for (int mt = 0; mt < 4; ++mt)
        #pragma unroll
        for (int nt = 0; nt < 2; ++nt)
            acc[mt][nt] = (f32x4){0.f, 0.f, 0.f, 0.f};

    #pragma unroll
    for (int ks = 0; ks < 12; ++ks) {
        bf16x8 a[4], b[2];
        #pragma unroll
        for (int mt = 0; mt < 4; ++mt)
            a[mt] = *(const bf16x8*)(abase + (mt * 12 + ks) * 512);
        #pragma unroll
        for (int nt = 0; nt < 2; ++nt)
            b[nt] = *(const bf16x8*)&Bl[(size_t)((nt * 12 + ks) * 64 + l) * 8];
        #pragma unroll
        for (int mt = 0; mt < 4; ++mt)
            #pragma unroll
            for (int nt = 0; nt < 2; ++nt)
                acc[mt][nt] = __builtin_amdgcn_mfma_f32_16x16x32_bf16(
                    a[mt], b[nt], acc[mt][nt], 0, 0, 0);
    }

    // ---- phase 4: clamp, margin at label, fixed-max partial LSE ----
    #pragma unroll
    for (int mt = 0; mt < 4; ++mt) {
        #pragma unroll
        for (int rg = 0; rg < 4; ++rg) {
            const int r   = wid * 64 + mt * 16 + lg * 4 + rg;
            const int lab = labels[r];
            float acc4 = 0.f;
            #pragma unroll
            for (int nt = 0; nt < 2; ++nt) {
                int gc = c0 + nt * 16 + lr;
                float cosv = acc[mt][nt][rg];
                cosv = fminf(fmaxf(cosv, -1.f + EPS_), 1.f - EPS_);
                float zz = S_SCALE * cosv;
                if (gc == lab) {
                    float zm;
                    if (cosv > TH_) {
                        float sv = sqrtf(fmaxf(1.f - cosv * cosv, 0.f));
                        zm = S_SCALE * (cosv * COS_M_ - sv * SIN_M_);
                    } else {
                        zm = S_SCALE * (cosv - MM_);
                    }
                    zlabel[r] = zm;
                    zz = zm;
                }
                acc4 += exp2f(zz * LOG2E_ - BIGZ_);
            }
            float s = acc4;
            #pragma unroll
            for (int d = 1; d < 16; d <<= 1) s += __shfl_xor(s, d, 64);
            if (lr == 0) psum[(size_t)blk * BATCH + r] = s;
        }
    }
}

// ---------------------------------------------------------------------------
// Kernel 2: sum 3125 chunk-partials per row -> row loss.
// grid = 8 blocks x 512 threads; lane->row mapping keeps reads coalesced.
// ---------------------------------------------------------------------------
__global__ __launch_bounds__(512)
void arc_reduce(const float* __restrict__ psum, const float* __restrict__ zlabel,
                float* __restrict__ rowloss)
{
    const int tid = threadIdx.x;
    const int r   = blockIdx.x * 64 + (tid & 63);
    const int kg  = tid >> 6;                      // 0..7
    float s = 0.f;
    for (int k = kg; k < NCHK; k += 8)
        s += psum[(size_t)k * BATCH + r];
    __shared__ float sh[8][64];
    sh[kg][tid & 63] = s;
    __syncthreads();
    if (tid < 64) {
        float t = 0.f;
        #pragma unroll
        for (int w = 0; w < 8; ++w) t += sh[w][tid];
        rowloss[r] = LN2_ * (BIGZ_ + log2f(t)) - zlabel[r];
    }
}

// ---------------------------------------------------------------------------
// Kernel 3: mean over rows
// ---------------------------------------------------------------------------
__global__ __launch_bounds__(512)
void arc_mean(const float* __restrict__ rowloss, float* __restrict__ out)
{
    const int tid = threadIdx.x;
    float v = rowloss[tid];
    #pragma unroll
    for (int d = 1; d < 64; d <<= 1) v += __shfl_xor(v, d, 64);
    __shared__ float sv[8];
    if ((tid & 63) == 0) sv[tid >> 6] = v;
    __syncthreads();
    if (tid == 0) {
        float t = 0.f;
        #pragma unroll
        for (int w = 0; w < 8; ++w) t += sv[w];
        out[0] = t / (float)BATCH;
    }
}

extern "C" void kernel_launch(void* const* d_in, const int* in_sizes, int n_in,
                              void* d_out, int out_size, void* d_ws, size_t ws_size,
                              hipStream_t stream)
{
    (void)in_sizes; (void)n_in; (void)out_size; (void)ws_size;
    const float* emb    = (const float*)d_in[0];
    const int*   labels = (const int*)d_in[1];
    const float* weight = (const float*)d_in[2];
    float* out = (float*)d_out;

    float*  psum    = (float*)d_ws;                    // [NCHK][BATCH]  6.4 MB
    float*  zlabel  = psum + (size_t)NCHK * BATCH;     // [BATCH]
    float*  rowloss = zlabel + BATCH;                  // [BATCH]
    ushort* eP      = (ushort*)(rowloss + BATCH);      // packed bf16 E frags

    cvt_pack_e<<<(BATCH * EMBED / 8) / 256, 256, 0, stream>>>(emb, eP);
    arc_fused<<<NCHK, 512, 0, stream>>>(eP, labels, weight, psum, zlabel);
    arc_reduce<<<8, 512, 0, stream>>>(psum, zlabel, rowloss);
    arc_mean<<<1, 512, 0, stream>>>(rowloss, out);
}

// Round 9
// 184.352 us; speedup vs baseline: 1.1889x; 1.1889x over previous
//
#include <hip/hip_runtime.h>
#include <hip/hip_bf16.h>
#include <math.h>

#define C_CLASSES 100000
#define EMBED     384
#define BATCH     512
#define S_SCALE   64.0f
#define COS_M_    0.8775825618903728f
#define SIN_M_    0.479425538604203f
#define TH_       (-0.8775825618903728f)
#define MM_       0.2397127693021015f
#define EPS_      1e-7f
#define LOG2E_    1.4426950408889634f
#define LN2_      0.6931471805599453f
#define BIGZ_     92.33261191693459f      /* 64 * log2(e) */

#define CT    32                           // classes per block
#define NCHK  3125                         // 100000 / 32, exact (no tail!)

typedef __attribute__((ext_vector_type(8))) short bf16x8;
typedef __attribute__((ext_vector_type(4))) float f32x4;

__device__ inline ushort f2bf(float f) {
    unsigned u = __float_as_uint(f);
    unsigned r = (u + 0x7fffu + ((u >> 16) & 1u)) >> 16;   // RNE
    return (ushort)r;
}

// ---------------------------------------------------------------------------
// Kernel 0: convert E to bf16, packed in MFMA A-fragment order:
//   eP[((tile*12 + ks)*64 + lane)*8 + j] = bf16(E[tile*16 + (lane&15)]
//                                               [ks*32 + (lane>>4)*8 + j])
// ---------------------------------------------------------------------------
__global__ __launch_bounds__(256)
void cvt_pack_e(const float* __restrict__ emb, ushort* __restrict__ eP)
{
    int t = blockIdx.x * 256 + threadIdx.x;      // 0 .. 24575
    int lane = t & 63;
    int grp  = t >> 6;                           // tile*12 + ks
    int tile = grp / 12, ks = grp % 12;
    int lr = lane & 15, lg = lane >> 4;
    int row = tile * 16 + lr;
    int col = ks * 32 + lg * 8;
    const float4* src = (const float4*)(emb + (size_t)row * EMBED + col);
    float4 v0 = src[0], v1 = src[1];
    ushort4 o0, o1;
    o0.x = f2bf(v0.x); o0.y = f2bf(v0.y); o0.z = f2bf(v0.z); o0.w = f2bf(v0.w);
    o1.x = f2bf(v1.x); o1.y = f2bf(v1.y); o1.z = f2bf(v1.z); o1.w = f2bf(v1.w);
    ((ushort4*)eP)[t * 2]     = o0;
    ((ushort4*)eP)[t * 2 + 1] = o1;
}

// ---------------------------------------------------------------------------
// Kernel 1: fused, occupancy-first. Per block (32 classes, no tail):
//   read W fp32 global->reg (16 lanes/row, 6xfloat4), sumsq butterfly,
//   scale -> bf16 B-fragment-packed LDS (24 KB) -> sync ->
//   MFMA (8 waves x 4mt x 2nt x 12ks) with A-frags from L2-resident eP ->
//   margin + fixed-max partial LSE.
// grid = 3125 x 512; LDS 26 KB; launch_bounds(512,8) -> VGPR<=64,
// 4 blocks/CU = 32 waves/CU: cross-block phase overlap hides all latency.
// ---------------------------------------------------------------------------
__global__ __launch_bounds__(512, 8)
void arc_fused(const ushort* __restrict__ eP, const int* __restrict__ labels,
               const float* __restrict__ weight,
               float* __restrict__ psum, float* __restrict__ zlabel)
{
    __shared__ ushort Bl[(CT / 16) * 12 * 512];     // 24576 B packed bf16 B
    __shared__ int    labL[BATCH];                   // 2 KB

    const int tid = threadIdx.x;
    const int blk = blockIdx.x;
    const int c0  = blk * CT;

    labL[tid] = labels[tid];

    // ---- phase 1: normalize 32 rows (16 lanes/row), write packed LDS ----
    {
        const int c = tid >> 4;          // class within chunk (0..31)
        const int p = tid & 15;          // 16 lanes per class
        const float4* src = (const float4*)(weight + (size_t)(c0 + c) * EMBED);
        float4 v[6];
        float ss = 0.f;
        #pragma unroll
        for (int i = 0; i < 6; ++i) {
            v[i] = src[p + 16 * i];
            ss += v[i].x * v[i].x + v[i].y * v[i].y
                + v[i].z * v[i].z + v[i].w * v[i].w;
        }
        #pragma unroll
        for (int d = 1; d < 16; d <<= 1) ss += __shfl_xor(ss, d, 64);
        const float inv = (ss > 0.f) ? rsqrtf(ss) : 0.f;

        const int t2 = c >> 4, cl = c & 15;
        #pragma unroll
        for (int i = 0; i < 6; ++i) {
            int q   = p + 16 * i;            // quad index 0..95 (k = 4q..4q+3)
            int ks  = q >> 3;
            int lgp = (q >> 1) & 3;
            int jo  = (q & 1) * 4;
            ushort4 o;
            o.x = f2bf(v[i].x * inv); o.y = f2bf(v[i].y * inv);
            o.z = f2bf(v[i].z * inv); o.w = f2bf(v[i].w * inv);
            *(ushort4*)&Bl[(size_t)(((t2 * 12 + ks) * 64) + cl + 16 * lgp) * 8 + jo] = o;
        }
    }
    __syncthreads();     // packed B ready

    // ---- phase 2: MFMA, 8 waves x (4 Mtiles x 2 Ntiles), K=384 ----
    const int wid = tid >> 6, l = tid & 63;
    const int lr  = l & 15,  lg = l >> 4;

    const ushort* abase = eP + ((size_t)(wid * 4) * 12 * 64 + l) * 8;

    f32x4 acc[4][2];
    #pragma unroll
    for (int mt = 0; mt < 4; ++mt)
        #pragma unroll
        for (int nt = 0; nt < 2; ++nt)
            acc[mt][nt] = (f32x4){0.f, 0.f, 0.f, 0.f};

    #pragma unroll
    for (int ks = 0; ks < 12; ++ks) {
        bf16x8 a[4];
        #pragma unroll
        for (int mt = 0; mt < 4; ++mt)
            a[mt] = *(const bf16x8*)(abase + (mt * 12 + ks) * 512);
        #pragma unroll
        for (int nt = 0; nt < 2; ++nt) {
            bf16x8 b = *(const bf16x8*)&Bl[(size_t)((nt * 12 + ks) * 64 + l) * 8];
            #pragma unroll
            for (int mt = 0; mt < 4; ++mt)
                acc[mt][nt] = __builtin_amdgcn_mfma_f32_16x16x32_bf16(
                    a[mt], b, acc[mt][nt], 0, 0, 0);
        }
    }

    // ---- phase 3: clamp, margin at label, fixed-max partial LSE ----
    #pragma unroll
    for (int mt = 0; mt < 4; ++mt) {
        #pragma unroll
        for (int rg = 0; rg < 4; ++rg) {
            const int r   = wid * 64 + mt * 16 + lg * 4 + rg;
            const int lab = labL[r];
            float acc4 = 0.f;
            #pragma unroll
            for (int nt = 0; nt < 2; ++nt) {
                int gc = c0 + nt * 16 + lr;
                float cosv = acc[mt][nt][rg];
                cosv = fminf(fmaxf(cosv, -1.f + EPS_), 1.f - EPS_);
                float zz = S_SCALE * cosv;
                if (gc == lab) {
                    float zm;
                    if (cosv > TH_) {
                        float sv = sqrtf(fmaxf(1.f - cosv * cosv, 0.f));
                        zm = S_SCALE * (cosv * COS_M_ - sv * SIN_M_);
                    } else {
                        zm = S_SCALE * (cosv - MM_);
                    }
                    zlabel[r] = zm;
                    zz = zm;
                }
                acc4 += exp2f(zz * LOG2E_ - BIGZ_);
            }
            float s = acc4;
            #pragma unroll
            for (int d = 1; d < 16; d <<= 1) s += __shfl_xor(s, d, 64);
            if (lr == 0) psum[(size_t)blk * BATCH + r] = s;
        }
    }
}

// ---------------------------------------------------------------------------
// Kernel 2: sum 3125 chunk-partials per row -> row loss. One block per row
// (512 blocks -> all CUs busy; reads are L2/L3-resident).
// ---------------------------------------------------------------------------
__global__ __launch_bounds__(256)
void arc_reduce(const float* __restrict__ psum, const float* __restrict__ zlabel,
                float* __restrict__ rowloss)
{
    const int r = blockIdx.x;
    const int tid = threadIdx.x;
    float s = 0.f;
    for (int k = tid; k < NCHK; k += 256)
        s += psum[(size_t)k * BATCH + r];
    #pragma unroll
    for (int d = 1; d < 64; d <<= 1) s += __shfl_xor(s, d, 64);
    __shared__ float ssh[4];
    if ((tid & 63) == 0) ssh[tid >> 6] = s;
    __syncthreads();
    if (tid == 0) {
        float t = ssh[0] + ssh[1] + ssh[2] + ssh[3];
        rowloss[r] = LN2_ * (BIGZ_ + log2f(t)) - zlabel[r];
    }
}

// ---------------------------------------------------------------------------
// Kernel 3: mean over rows
// ---------------------------------------------------------------------------
__global__ __launch_bounds__(512)
void arc_mean(const float* __restrict__ rowloss, float* __restrict__ out)
{
    const int tid = threadIdx.x;
    float v = rowloss[tid];
    #pragma unroll
    for (int d = 1; d < 64; d <<= 1) v += __shfl_xor(v, d, 64);
    __shared__ float sv[8];
    if ((tid & 63) == 0) sv[tid >> 6] = v;
    __syncthreads();
    if (tid == 0) {
        float t = 0.f;
        #pragma unroll
        for (int w = 0; w < 8; ++w) t += sv[w];
        out[0] = t / (float)BATCH;
    }
}

extern "C" void kernel_launch(void* const* d_in, const int* in_sizes, int n_in,
                              void* d_out, int out_size, void* d_ws, size_t ws_size,
                              hipStream_t stream)
{
    (void)in_sizes; (void)n_in; (void)out_size; (void)ws_size;
    const float* emb    = (const float*)d_in[0];
    const int*   labels = (const int*)d_in[1];
    const float* weight = (const float*)d_in[2];
    float* out = (float*)d_out;

    float*  psum    = (float*)d_ws;                    // [NCHK][BATCH]  6.4 MB
    float*  zlabel  = psum + (size_t)NCHK * BATCH;     // [BATCH]
    float*  rowloss = zlabel + BATCH;                  // [BATCH]
    ushort* eP      = (ushort*)(rowloss + BATCH);      // packed bf16 E frags

    cvt_pack_e<<<(BATCH * EMBED / 8) / 256, 256, 0, stream>>>(emb, eP);
    arc_fused<<<NCHK, 512, 0, stream>>>(eP, labels, weight, psum, zlabel);
    arc_reduce<<<BATCH, 256, 0, stream>>>(psum, zlabel, rowloss);
    arc_mean<<<1, 512, 0, stream>>>(rowloss, out);
}

// Round 10
// 128.545 us; speedup vs baseline: 1.7051x; 1.4341x over previous
//
#include <hip/hip_runtime.h>
#include <hip/hip_bf16.h>
#include <math.h>

#define C_CLASSES 100000
#define EMBED     384
#define BATCH     512
#define S_SCALE   64.0f
#define COS_M_    0.8775825618903728f
#define SIN_M_    0.479425538604203f
#define TH_       (-0.8775825618903728f)
#define MM_       0.2397127693021015f
#define EPS_      1e-7f
#define LOG2E_    1.4426950408889634f
#define LN2_      0.6931471805599453f
#define BIGZ_     92.33261191693459f      /* 64 * log2(e) */

#define CT     64
#define NCH    1563                        // ceil(100000/64)
#define WTILES 6252                        // 6250 real 16-class tiles + 2 pad

typedef __attribute__((ext_vector_type(8))) short bf16x8;
typedef __attribute__((ext_vector_type(4))) float f32x4;

#define AS1 __attribute__((address_space(1)))
#define AS3 __attribute__((address_space(3)))

__device__ inline ushort f2bf(float f) {
    unsigned u = __float_as_uint(f);
    unsigned r = (u + 0x7fffu + ((u >> 16) & 1u)) >> 16;   // RNE
    return (ushort)r;
}

// ---------------------------------------------------------------------------
// Kernel 0: convert E to bf16, packed in MFMA A-fragment order:
//   eP[((tile*12 + ks)*64 + lane)*8 + j] = bf16(E[tile*16 + (lane&15)]
//                                               [ks*32 + (lane>>4)*8 + j])
// ---------------------------------------------------------------------------
__global__ __launch_bounds__(256)
void cvt_pack_e(const float* __restrict__ emb, ushort* __restrict__ eP)
{
    int t = blockIdx.x * 256 + threadIdx.x;      // 0 .. 24575
    int lane = t & 63;
    int grp  = t >> 6;                           // tile*12 + ks
    int tile = grp / 12, ks = grp % 12;
    int lr = lane & 15, lg = lane >> 4;
    int row = tile * 16 + lr;
    int col = ks * 32 + lg * 8;
    const float4* src = (const float4*)(emb + (size_t)row * EMBED + col);
    float4 v0 = src[0], v1 = src[1];
    ushort4 o0, o1;
    o0.x = f2bf(v0.x); o0.y = f2bf(v0.y); o0.z = f2bf(v0.z); o0.w = f2bf(v0.w);
    o1.x = f2bf(v1.x); o1.y = f2bf(v1.y); o1.z = f2bf(v1.z); o1.w = f2bf(v1.w);
    ((ushort4*)eP)[t * 2]     = o0;
    ((ushort4*)eP)[t * 2 + 1] = o1;
}

// ---------------------------------------------------------------------------
// Kernel 1: stream W once: row-normalize in registers, write bf16 packed in
// MFMA B-fragment order. 16 lanes per row; grid = 6250 blocks x 256 threads.
// ---------------------------------------------------------------------------
__global__ __launch_bounds__(256)
void norm_pack_w(const float* __restrict__ weight, ushort* __restrict__ wB)
{
    const int row = blockIdx.x * 16 + (threadIdx.x >> 4);
    const int p   = threadIdx.x & 15;
    const float4* src = (const float4*)(weight + (size_t)row * EMBED) + p;

    float4 v[6];
    float ss = 0.f;
    #pragma unroll
    for (int i = 0; i < 6; ++i) {
        v[i] = src[16 * i];
        ss += v[i].x * v[i].x + v[i].y * v[i].y
            + v[i].z * v[i].z + v[i].w * v[i].w;
    }
    #pragma unroll
    for (int d = 1; d < 16; d <<= 1) ss += __shfl_xor(ss, d, 64);
    const float inv = (ss > 0.f) ? rsqrtf(ss) : 0.f;

    const size_t tbase = ((size_t)(row >> 4) * 12) * 512 + (row & 15) * 8;
    #pragma unroll
    for (int i = 0; i < 6; ++i) {
        int q = p + 16 * i;                   // quad index 0..95 (k = 4q)
        ushort4 o;
        o.x = f2bf(v[i].x * inv); o.y = f2bf(v[i].y * inv);
        o.z = f2bf(v[i].z * inv); o.w = f2bf(v[i].w * inv);
        size_t dst = tbase + (size_t)(q >> 3) * 512
                   + (size_t)((q >> 1) & 3) * 128 + (q & 1) * 4;
        *(ushort4*)&wB[dst] = o;
    }
}

// ---------------------------------------------------------------------------
// Kernel 2: BM=256 GEMM. A-fragments persistent in registers (2 Mtiles/wave,
// 96 VGPR, loaded once from L2). Chunk loop: double-buffered DMA stage of the
// 48 KB B-slice (issued BEFORE compute), 1 barrier/chunk, MFMA from LDS,
// fused margin + fixed-max LSE epilogue.
// grid = 512 (2 Mgroups x 256) x 512 thr; LDS 96 KB -> 1 block/CU, VGPR<=256.
// ---------------------------------------------------------------------------
__global__ __launch_bounds__(512, 2)
void arc_gemm256(const ushort* __restrict__ eP, const ushort* __restrict__ wB,
                 const int* __restrict__ labels,
                 float* __restrict__ psum, float* __restrict__ zlabel)
{
    __shared__ ushort Bl[2][CT / 16 * 12 * 512];   // 2 x 49152 B

    const int tid = threadIdx.x;
    const int b   = blockIdx.x;            // 0..511
    const int mg  = b >> 8;                // M group 0/1 (rows mg*256..+255)
    const int bk  = b & 255;               // chunk stream id
    const int nch = 6 + ((bk < (NCH - 6 * 256)) ? 1 : 0);   // 27 blocks do 7

    const int wid = tid >> 6, l = tid & 63;
    const int lr  = l & 15,  lg = l >> 4;

    // ---- persistent A fragments: 2 Mtiles x 12 ks (96 VGPR) ----
    bf16x8 A[2][12];
    #pragma unroll
    for (int mt = 0; mt < 2; ++mt)
        #pragma unroll
        for (int ks = 0; ks < 12; ++ks)
            A[mt][ks] = *(const bf16x8*)(
                eP + (size_t)((mg * 16 + wid * 2 + mt) * 12 + ks) * 512 + l * 8);

    // labels for the 8 rows this thread owns (fixed across chunks)
    int labr[8];
    #pragma unroll
    for (int q = 0; q < 8; ++q)
        labr[q] = labels[mg * 256 + wid * 32 + (q >> 2) * 16 + lg * 4 + (q & 3)];

    // ---- DMA stage of one chunk's 48 KB B-slice into Bl[buf] ----
    // wB layout == LDS layout (fragment-packed) -> purely linear copy.
    const int ldgrp = tid & ~63;           // wave-uniform LDS base component

    // prologue: stage chunk bk into buffer 0
    {
        const AS1 uint* g = (const AS1 uint*)(wB + (size_t)bk * 24576);
        #pragma unroll
        for (int j = 0; j < 6; ++j) {
            const AS1 uint* gp = g + (size_t)(j * 512 + tid) * 4;
            AS3 uint* lp = (AS3 uint*)&Bl[0][0] + (size_t)(j * 512 + ldgrp) * 4;
            __builtin_amdgcn_global_load_lds(gp, lp, 16, 0, 0);
        }
    }
    __syncthreads();

    int ch  = bk;
    int cur = 0;
    for (int k = 0; k < nch; ++k) {
        // ---- issue next chunk's stage into the other buffer (early) ----
        if (k + 1 < nch) {
            const AS1 uint* g = (const AS1 uint*)(wB + (size_t)(ch + 256) * 24576);
            #pragma unroll
            for (int j = 0; j < 6; ++j) {
                const AS1 uint* gp = g + (size_t)(j * 512 + tid) * 4;
                AS3 uint* lp = (AS3 uint*)&Bl[cur ^ 1][0]
                             + (size_t)(j * 512 + ldgrp) * 4;
                __builtin_amdgcn_global_load_lds(gp, lp, 16, 0, 0);
            }
        }

        const int c0 = ch * CT;

        // ---- MFMA: 2 Mtiles x 4 Ntiles x 12 ks from Bl[cur] ----
        f32x4 acc[2][4];
        #pragma unroll
        for (int mt = 0; mt < 2; ++mt)
            #pragma unroll
            for (int nt = 0; nt < 4; ++nt)
                acc[mt][nt] = (f32x4){0.f, 0.f, 0.f, 0.f};

        #pragma unroll
        for (int ks = 0; ks < 12; ++ks) {
            bf16x8 bfr[4];
            #pragma unroll
            for (int nt = 0; nt < 4; ++nt)
                bfr[nt] = *(const bf16x8*)&Bl[cur][(size_t)((nt * 12 + ks) * 64 + l) * 8];
            #pragma unroll
            for (int mt = 0; mt < 2; ++mt)
                #pragma unroll
                for (int nt = 0; nt < 4; ++nt)
                    acc[mt][nt] = __builtin_amdgcn_mfma_f32_16x16x32_bf16(
                        A[mt][ks], bfr[nt], acc[mt][nt], 0, 0, 0);
        }

        // ---- epilogue: clamp, margin at label, fixed-max partial LSE ----
        #pragma unroll
        for (int mt = 0; mt < 2; ++mt) {
            #pragma unroll
            for (int rg = 0; rg < 4; ++rg) {
                const int r   = mg * 256 + wid * 32 + mt * 16 + lg * 4 + rg;
                const int lab = labr[mt * 4 + rg];
                float acc4 = 0.f;
                #pragma unroll
                for (int nt = 0; nt < 4; ++nt) {
                    int gc = c0 + nt * 16 + lr;
                    float cosv = acc[mt][nt][rg];
                    cosv = fminf(fmaxf(cosv, -1.f + EPS_), 1.f - EPS_);
                    float zz = S_SCALE * cosv;
                    if (gc == lab) {
                        float zm;
                        if (cosv > TH_) {
                            float sv = sqrtf(fmaxf(1.f - cosv * cosv, 0.f));
                            zm = S_SCALE * (cosv * COS_M_ - sv * SIN_M_);
                        } else {
                            zm = S_SCALE * (cosv - MM_);
                        }
                        zlabel[r] = zm;
                        zz = zm;
                    }
                    float z = (gc >= C_CLASSES) ? -1e30f : zz * LOG2E_ - BIGZ_;
                    acc4 += exp2f(z);
                }
                float s = acc4;
                #pragma unroll
                for (int d = 1; d < 16; d <<= 1) s += __shfl_xor(s, d, 64);
                if (lr == 0) psum[(size_t)ch * BATCH + r] = s;
            }
        }

        // barrier: staged data visible (syncthreads drains vmcnt) AND all
        // waves are done reading Bl[cur] before it is restaged next iter.
        __syncthreads();
        cur ^= 1;
        ch  += 256;
    }
}

// ---------------------------------------------------------------------------
// Kernel 3: sum 1563 chunk-partials per row -> row loss
// ---------------------------------------------------------------------------
__global__ __launch_bounds__(256)
void arc_reduce(const float* __restrict__ psum, const float* __restrict__ zlabel,
                float* __restrict__ rowloss)
{
    const int r = blockIdx.x;
    const int tid = threadIdx.x;
    float s = 0.f;
    for (int k = tid; k < NCH; k += 256)
        s += psum[(size_t)k * BATCH + r];
    #pragma unroll
    for (int d = 1; d < 64; d <<= 1) s += __shfl_xor(s, d, 64);
    __shared__ float ssh[4];
    if ((tid & 63) == 0) ssh[tid >> 6] = s;
    __syncthreads();
    if (tid == 0) {
        float t = ssh[0] + ssh[1] + ssh[2] + ssh[3];
        rowloss[r] = LN2_ * (BIGZ_ + log2f(t)) - zlabel[r];
    }
}

// ---------------------------------------------------------------------------
// Kernel 4: mean over rows
// ---------------------------------------------------------------------------
__global__ __launch_bounds__(512)
void arc_mean(const float* __restrict__ rowloss, float* __restrict__ out)
{
    const int tid = threadIdx.x;
    float v = rowloss[tid];
    #pragma unroll
    for (int d = 1; d < 64; d <<= 1) v += __shfl_xor(v, d, 64);
    __shared__ float sv[8];
    if ((tid & 63) == 0) sv[tid >> 6] = v;
    __syncthreads();
    if (tid == 0) {
        float t = 0.f;
        #pragma unroll
        for (int w = 0; w < 8; ++w) t += sv[w];
        out[0] = t / (float)BATCH;
    }
}

extern "C" void kernel_launch(void* const* d_in, const int* in_sizes, int n_in,
                              void* d_out, int out_size, void* d_ws, size_t ws_size,
                              hipStream_t stream)
{
    (void)in_sizes; (void)n_in; (void)out_size; (void)ws_size;
    const float* emb    = (const float*)d_in[0];
    const int*   labels = (const int*)d_in[1];
    const float* weight = (const float*)d_in[2];
    float* out = (float*)d_out;

    float*  psum    = (float*)d_ws;                    // [NCH][BATCH]  3.2 MB
    float*  zlabel  = psum + (size_t)NCH * BATCH;      // [BATCH]
    float*  rowloss = zlabel + BATCH;                  // [BATCH]
    ushort* eP      = (ushort*)(rowloss + BATCH);      // packed bf16 E frags
    ushort* wB      = eP + (size_t)BATCH * EMBED;      // packed bf16 W frags

    cvt_pack_e<<<(BATCH * EMBED / 8) / 256, 256, 0, stream>>>(emb, eP);
    norm_pack_w<<<C_CLASSES / 16, 256, 0, stream>>>(weight, wB);
    arc_gemm256<<<512, 512, 0, stream>>>(eP, wB, labels, psum, zlabel);
    arc_reduce<<<BATCH, 256, 0, stream>>>(psum, zlabel, rowloss);
    arc_mean<<<1, 512, 0, stream>>>(rowloss, out);
}

// Round 11
// 109.135 us; speedup vs baseline: 2.0083x; 1.1778x over previous
//
#include <hip/hip_runtime.h>
#include <hip/hip_bf16.h>
#include <math.h>

#define C_CLASSES 100000
#define EMBED     384
#define BATCH     512
#define S_SCALE   64.0f
#define COS_M_    0.8775825618903728f
#define SIN_M_    0.479425538604203f
#define TH_       (-0.8775825618903728f)
#define MM_       0.2397127693021015f
#define EPS_      1e-7f
#define LOG2E_    1.4426950408889634f
#define LN2_      0.6931471805599453f
#define BIGZ_     92.33261191693459f      /* 64 * log2(e) */

#define CT    64
#define NCH   1563                         // ceil(100000/64); last chunk: 32 pad

typedef __attribute__((ext_vector_type(8))) short bf16x8;
typedef __attribute__((ext_vector_type(4))) float f32x4;

__device__ inline ushort f2bf(float f) {
    unsigned u = __float_as_uint(f);
    unsigned r = (u + 0x7fffu + ((u >> 16) & 1u)) >> 16;   // RNE
    return (ushort)r;
}

// ---------------------------------------------------------------------------
// Kernel 0: convert E to bf16, packed in MFMA A-fragment order:
//   eP[((tile*12 + ks)*64 + lane)*8 + j] = bf16(E[tile*16 + (lane&15)]
//                                               [ks*32 + (lane>>4)*8 + j])
// ---------------------------------------------------------------------------
__global__ __launch_bounds__(256)
void cvt_pack_e(const float* __restrict__ emb, ushort* __restrict__ eP)
{
    int t = blockIdx.x * 256 + threadIdx.x;      // 0 .. 24575
    int lane = t & 63;
    int grp  = t >> 6;                           // tile*12 + ks
    int tile = grp / 12, ks = grp % 12;
    int lr = lane & 15, lg = lane >> 4;
    int row = tile * 16 + lr;
    int col = ks * 32 + lg * 8;
    const float4* src = (const float4*)(emb + (size_t)row * EMBED + col);
    float4 v0 = src[0], v1 = src[1];
    ushort4 o0, o1;
    o0.x = f2bf(v0.x); o0.y = f2bf(v0.y); o0.z = f2bf(v0.z); o0.w = f2bf(v0.w);
    o1.x = f2bf(v1.x); o1.y = f2bf(v1.y); o1.z = f2bf(v1.z); o1.w = f2bf(v1.w);
    ((ushort4*)eP)[t * 2]     = o0;
    ((ushort4*)eP)[t * 2 + 1] = o1;
}

// ---------------------------------------------------------------------------
// Kernel 1: fully fused, single pass over W (read from HBM exactly once).
// Per block (64-class chunk, 512 thr, 8 waves):
//   phase 1: raw W global->reg (8 lanes/row x 12 float4, coalesced),
//            sumsq 8-lane butterfly, scale -> bf16, store straight into
//            fragment-packed LDS Bl (48 KB)            -> one __syncthreads
//   phase 2: MFMA 8 waves x 4Mt x 4Nt x 12ks; A from L2-resident eP
//            (fragment-packed, coalesced), B linear ds_read_b128 from Bl
//   phase 3: clamp + margin-at-label + fixed-max partial LSE, one
//            16-lane reduce, contiguous psum write.
// launch_bounds(512,4): 128-reg budget (proven 64V+64A in r7 body);
// LDS 48KB -> up to 3 blocks/CU for cross-block phase overlap.
// ---------------------------------------------------------------------------
__global__ __launch_bounds__(512, 4)
void arc_fused64(const ushort* __restrict__ eP, const int* __restrict__ labels,
                 const float* __restrict__ weight,
                 float* __restrict__ psum, float* __restrict__ zlabel)
{
    __shared__ ushort Bl[(CT / 16) * 12 * 512];    // 24576 ushorts = 49152 B

    const int tid = threadIdx.x;
    const int blk = blockIdx.x;
    const int c0  = blk * CT;

    // ---- phase 1: normalize 64 rows (8 lanes/row), pack to LDS ----
    {
        const int c = tid >> 3;              // class within chunk 0..63
        const int p = tid & 7;               // 8 lanes per class
        int row = c0 + c;
        if (row >= C_CLASSES) row = C_CLASSES - 1;    // pad rows: clamp
        const float4* src = (const float4*)(weight + (size_t)row * EMBED) + p;

        float4 v[12];
        float ss = 0.f;
        #pragma unroll
        for (int i = 0; i < 12; ++i) {
            v[i] = src[8 * i];
            ss += v[i].x * v[i].x + v[i].y * v[i].y
                + v[i].z * v[i].z + v[i].w * v[i].w;
        }
        #pragma unroll
        for (int d = 1; d < 8; d <<= 1) ss += __shfl_xor(ss, d, 64);
        const float inv = (ss > 0.f) ? rsqrtf(ss) : 0.f;

        const int t2 = c >> 4, cl = c & 15;
        #pragma unroll
        for (int i = 0; i < 12; ++i) {
            int q   = p + 8 * i;             // quad index 0..95 (k = 4q..4q+3)
            int ks  = q >> 3;
            int lgp = (q >> 1) & 3;
            int jo  = (q & 1) * 4;
            ushort4 o;
            o.x = f2bf(v[i].x * inv); o.y = f2bf(v[i].y * inv);
            o.z = f2bf(v[i].z * inv); o.w = f2bf(v[i].w * inv);
            *(ushort4*)&Bl[(size_t)(((t2 * 12 + ks) * 64) + cl + 16 * lgp) * 8 + jo] = o;
        }
    }
    __syncthreads();     // packed B ready

    // ---- phase 2: MFMA, 8 waves x (4 Mtiles x 4 Ntiles), K=384 ----
    const int wid = tid >> 6, l = tid & 63;
    const int lr  = l & 15,  lg = l >> 4;

    const ushort* abase = eP + ((size_t)(wid * 4) * 12 * 64 + l) * 8;

    f32x4 acc[4][4];
    #pragma unroll
    for (int mt = 0; mt < 4; ++mt)
        #pragma unroll
        for (int nt = 0; nt < 4; ++nt)
            acc[mt][nt] = (f32x4){0.f, 0.f, 0.f, 0.f};

    #pragma unroll
    for (int ks = 0; ks < 12; ++ks) {
        bf16x8 a[4], b[4];
        #pragma unroll
        for (int mt = 0; mt < 4; ++mt)
            a[mt] = *(const bf16x8*)(abase + (mt * 12 + ks) * 512);
        #pragma unroll
        for (int nt = 0; nt < 4; ++nt)
            b[nt] = *(const bf16x8*)&Bl[(size_t)((nt * 12 + ks) * 64 + l) * 8];
        #pragma unroll
        for (int mt = 0; mt < 4; ++mt)
            #pragma unroll
            for (int nt = 0; nt < 4; ++nt)
                acc[mt][nt] = __builtin_amdgcn_mfma_f32_16x16x32_bf16(
                    a[mt], b[nt], acc[mt][nt], 0, 0, 0);
    }

    // ---- phase 3: clamp, margin at label, fixed-max partial LSE ----
    #pragma unroll
    for (int mt = 0; mt < 4; ++mt) {
        #pragma unroll
        for (int rg = 0; rg < 4; ++rg) {
            const int r   = wid * 64 + mt * 16 + lg * 4 + rg;
            const int lab = labels[r];
            float acc4 = 0.f;
            #pragma unroll
            for (int nt = 0; nt < 4; ++nt) {
                int gc = c0 + nt * 16 + lr;
                float cosv = acc[mt][nt][rg];
                cosv = fminf(fmaxf(cosv, -1.f + EPS_), 1.f - EPS_);
                float zz = S_SCALE * cosv;
                if (gc == lab) {
                    float zm;
                    if (cosv > TH_) {
                        float sv = sqrtf(fmaxf(1.f - cosv * cosv, 0.f));
                        zm = S_SCALE * (cosv * COS_M_ - sv * SIN_M_);
                    } else {
                        zm = S_SCALE * (cosv - MM_);
                    }
                    zlabel[r] = zm;
                    zz = zm;
                }
                float z = (gc >= C_CLASSES) ? -1e30f : zz * LOG2E_ - BIGZ_;
                acc4 += exp2f(z);
            }
            float s = acc4;
            #pragma unroll
            for (int d = 1; d < 16; d <<= 1) s += __shfl_xor(s, d, 64);
            if (lr == 0) psum[(size_t)blk * BATCH + r] = s;
        }
    }
}

// ---------------------------------------------------------------------------
// Kernel 2: sum 1563 chunk-partials per row -> row loss
// ---------------------------------------------------------------------------
__global__ __launch_bounds__(256)
void arc_reduce(const float* __restrict__ psum, const float* __restrict__ zlabel,
                float* __restrict__ rowloss)
{
    const int r = blockIdx.x;
    const int tid = threadIdx.x;
    float s = 0.f;
    for (int k = tid; k < NCH; k += 256)
        s += psum[(size_t)k * BATCH + r];
    #pragma unroll
    for (int d = 1; d < 64; d <<= 1) s += __shfl_xor(s, d, 64);
    __shared__ float ssh[4];
    if ((tid & 63) == 0) ssh[tid >> 6] = s;
    __syncthreads();
    if (tid == 0) {
        float t = ssh[0] + ssh[1] + ssh[2] + ssh[3];
        rowloss[r] = LN2_ * (BIGZ_ + log2f(t)) - zlabel[r];
    }
}

// ---------------------------------------------------------------------------
// Kernel 3: mean over rows
// ---------------------------------------------------------------------------
__global__ __launch_bounds__(512)
void arc_mean(const float* __restrict__ rowloss, float* __restrict__ out)
{
    const int tid = threadIdx.x;
    float v = rowloss[tid];
    #pragma unroll
    for (int d = 1; d < 64; d <<= 1) v += __shfl_xor(v, d, 64);
    __shared__ float sv[8];
    if ((tid & 63) == 0) sv[tid >> 6] = v;
    __syncthreads();
    if (tid == 0) {
        float t = 0.f;
        #pragma unroll
        for (int w = 0; w < 8; ++w) t += sv[w];
        out[0] = t / (float)BATCH;
    }
}

extern "C" void kernel_launch(void* const* d_in, const int* in_sizes, int n_in,
                              void* d_out, int out_size, void* d_ws, size_t ws_size,
                              hipStream_t stream)
{
    (void)in_sizes; (void)n_in; (void)out_size; (void)ws_size;
    const float* emb    = (const float*)d_in[0];
    const int*   labels = (const int*)d_in[1];
    const float* weight = (const float*)d_in[2];
    float* out = (float*)d_out;

    float*  psum    = (float*)d_ws;                    // [NCH][BATCH]  3.2 MB
    float*  zlabel  = psum + (size_t)NCH * BATCH;      // [BATCH]
    float*  rowloss = zlabel + BATCH;                  // [BATCH]
    ushort* eP      = (ushort*)(rowloss + BATCH);      // packed bf16 E frags

    cvt_pack_e<<<(BATCH * EMBED / 8) / 256, 256, 0, stream>>>(emb, eP);
    arc_fused64<<<NCH, 512, 0, stream>>>(eP, labels, weight, psum, zlabel);
    arc_reduce<<<BATCH, 256, 0, stream>>>(psum, zlabel, rowloss);
    arc_mean<<<1, 512, 0, stream>>>(rowloss, out);
}